// Round 6
// baseline (109.005 us; speedup 1.0000x reference)
//
#include <hip/hip_runtime.h>

#define BB 16
#define NN 4096
#define HQ (BB * NN)        // 65536 queries per direction
#define QT (2 * HQ)         // 131072 total
#define NSLICE 8
#define DBS (NN / NSLICE)   // 512 db points per block
#define WPTS (DBS / 4)      // 128 db points per wave
#define NGRP (WPTS / 4)     // 32 groups of 4 points per wave
#define PQ 16               // queries per lane
#define QW (64 * PQ)        // 1024 queries per block
#define NQC (NN / QW)       // 4 query chunks per batch
#define RBLOCKS (QT / 4 / 256)  // 128 reduce blocks

typedef float v2f __attribute__((ext_vector_type(2)));
typedef float v4f __attribute__((ext_vector_type(4)));

// d = a*b + c, packed fp32 (VOP3P). Rounds 3-5 proved the C-level vector
// builtins scalarize; inline asm guarantees the pk form.
__device__ __forceinline__ v2f pk_fma(v2f a, v2f b, v2f c) {
  v2f d;
  asm("v_pk_fma_f32 %0, %1, %2, %3" : "=v"(d) : "v"(a), "v"(b), "v"(c));
  return d;
}
// Both result halves use a.x (op_sel broadcast-lo of src0).
__device__ __forceinline__ v2f pk_fma_bl(v2f a, v2f b, v2f c) {
  v2f d;
  asm("v_pk_fma_f32 %0, %1, %2, %3 op_sel:[0,0,0] op_sel_hi:[0,1,1]"
      : "=v"(d) : "v"(a), "v"(b), "v"(c));
  return d;
}
// Both result halves use a.y (op_sel broadcast-hi of src0).
__device__ __forceinline__ v2f pk_fma_bh(v2f a, v2f b, v2f c) {
  v2f d;
  asm("v_pk_fma_f32 %0, %1, %2, %3 op_sel:[1,0,0] op_sel_hi:[1,1,1]"
      : "=v"(d) : "v"(a), "v"(b), "v"(c));
  return d;
}

// Block id bits: slice[0:2], qc[3:4], b[5:8], dir[9]. 1024 blocks.
// 4 waves share one 1024-query set (PQ=16/lane, packed 2-per-VGPR-pair via
// op_sel); each wave owns 128 pts of the block's 512-pt db slice in LDS.
// Inner: per 4-pt group per query = 4 v_pk_fma_f32 + 2 v_min3_f32.
// 1-group LDS prefetch pipeline hides ds_read latency.
__global__ __launch_bounds__(256, 4) void chamfer_partial(
    const float* __restrict__ pred, const float* __restrict__ target,
    float* __restrict__ partial, unsigned int* __restrict__ cnt) {
  const int bid = blockIdx.x;
  const int slice = bid & (NSLICE - 1);
  const int qc = (bid >> 3) & (NQC - 1);
  const int b = (bid >> 5) & (BB - 1);
  const int dir = bid >> 9;
  const int t = threadIdx.x;
  const int lane = t & 63;
  const int wid = t >> 6;

  if (bid == 0 && t == 0) *cnt = 0;  // arrival counter for reduce (ws poisoned)

  // 16 KB: staging uses first 6 KB (3x512 floats); combine reuses 16 KB.
  __shared__ float smem[4096];
  float* sTX = smem;
  float* sTY = smem + DBS;
  float* sT2 = smem + 2 * DBS;

  // Stage 512 db points (opposite cloud), 2 per thread, SoA + |t|^2.
  const float2* __restrict__ dsrc = (const float2*)(dir ? pred : target);
  {
    const float4 two = ((const float4*)(dsrc + b * NN + slice * DBS))[t];
    ((float2*)sTX)[t] = {two.x, two.z};
    ((float2*)sTY)[t] = {two.y, two.w};
    ((float2*)sT2)[t] = {__builtin_fmaf(two.x, two.x, two.y * two.y),
                         __builtin_fmaf(two.z, two.z, two.w * two.w)};
  }

  // This lane's 16 queries, packed two per VGPR pair: nxp[k2]=(nx_{2k2},
  // nx_{2k2+1}). m = t2 - 2qx*tx - 2qy*ty; q2 added at the combine stage.
  const float2* __restrict__ qsrc = (const float2*)(dir ? target : pred);
  const int qbase = b * NN + qc * QW + lane;
  v2f nxp[PQ / 2], nyp[PQ / 2];
  float acc[PQ];
#pragma unroll
  for (int k2 = 0; k2 < PQ / 2; ++k2) {
    const float2 QA = qsrc[qbase + (2 * k2) * 64];
    const float2 QB = qsrc[qbase + (2 * k2 + 1) * 64];
    nxp[k2] = {-2.0f * QA.x, -2.0f * QB.x};
    nyp[k2] = {-2.0f * QA.y, -2.0f * QB.y};
    acc[2 * k2] = 3.4e38f;
    acc[2 * k2 + 1] = 3.4e38f;
  }
  __syncthreads();

  const v4f* __restrict__ gx = (const v4f*)sTX + wid * NGRP;
  const v4f* __restrict__ gy = (const v4f*)sTY + wid * NGRP;
  const v4f* __restrict__ gs = (const v4f*)sT2 + wid * NGRP;
  v4f x4 = gx[0], y4 = gy[0], s4 = gs[0];
  for (int g = 0; g < NGRP; ++g) {
    // Prefetch next group (g=NGRP-1 overreads into adjacent smem: harmless).
    const v4f xn = gx[g + 1], yn = gy[g + 1], sn = gs[g + 1];
    const v2f xlo = __builtin_shufflevector(x4, x4, 0, 1);
    const v2f xhi = __builtin_shufflevector(x4, x4, 2, 3);
    const v2f ylo = __builtin_shufflevector(y4, y4, 0, 1);
    const v2f yhi = __builtin_shufflevector(y4, y4, 2, 3);
    const v2f slo = __builtin_shufflevector(s4, s4, 0, 1);
    const v2f shi = __builtin_shufflevector(s4, s4, 2, 3);
#pragma unroll
    for (int k2 = 0; k2 < PQ / 2; ++k2) {
      v2f r = pk_fma_bl(nyp[k2], ylo, slo);
      r = pk_fma_bl(nxp[k2], xlo, r);
      acc[2 * k2] = fminf(acc[2 * k2], fminf(r.x, r.y));  // v_min3_f32
      r = pk_fma_bl(nyp[k2], yhi, shi);
      r = pk_fma_bl(nxp[k2], xhi, r);
      acc[2 * k2] = fminf(acc[2 * k2], fminf(r.x, r.y));
      r = pk_fma_bh(nyp[k2], ylo, slo);
      r = pk_fma_bh(nxp[k2], xlo, r);
      acc[2 * k2 + 1] = fminf(acc[2 * k2 + 1], fminf(r.x, r.y));
      r = pk_fma_bh(nyp[k2], yhi, shi);
      r = pk_fma_bh(nxp[k2], xhi, r);
      acc[2 * k2 + 1] = fminf(acc[2 * k2 + 1], fminf(r.x, r.y));
    }
    x4 = xn;
    y4 = yn;
    s4 = sn;
  }

  __syncthreads();  // all waves done reading db before smem reuse
#pragma unroll
  for (int k = 0; k < PQ; ++k) smem[(k * 4 + wid) * 64 + lane] = acc[k];
  __syncthreads();

  // Thread t combines the 4 wave-mins for queries k=wid*4..wid*4+3 and adds
  // q2 = |Q|^2 = 0.25*(nx^2+ny^2) (every thread holds every query's nx,ny).
  const int pbase = slice * QT + dir * HQ + b * NN + qc * QW + lane;
#pragma unroll
  for (int j = 0; j < 4; ++j) {
    const int k = wid * 4 + j;
    const float m = fminf(fminf(smem[(k * 4 + 0) * 64 + lane],
                                smem[(k * 4 + 1) * 64 + lane]),
                          fminf(smem[(k * 4 + 2) * 64 + lane],
                                smem[(k * 4 + 3) * 64 + lane]));
    const float nx = (k & 1) ? nxp[k >> 1].y : nxp[k >> 1].x;
    const float ny = (k & 1) ? nyp[k >> 1].y : nyp[k >> 1].x;
    const float q2 = 0.25f * __builtin_fmaf(nx, nx, ny * ny);
    partial[pbase + k * 64] = m + q2;
  }
}

// Min over 8 slices (float4-vectorized; values are final d2), block-sum;
// last-arriving block folds the 128 block-sums into the two outputs.
__global__ __launch_bounds__(256) void chamfer_reduce(
    const float4* __restrict__ partial4, float* __restrict__ bsum,
    unsigned int* __restrict__ cnt, float* __restrict__ out) {
  const int i = blockIdx.x * 256 + threadIdx.x;  // 0 .. QT/4, 128 blocks
  float4 m = partial4[i];
#pragma unroll
  for (int s = 1; s < NSLICE; ++s) {
    const float4 w = partial4[s * (QT / 4) + i];
    m.x = fminf(m.x, w.x);
    m.y = fminf(m.y, w.y);
    m.z = fminf(m.z, w.z);
    m.w = fminf(m.w, w.w);
  }
  float v = (m.x + m.y) + (m.z + m.w);

#pragma unroll
  for (int off = 32; off > 0; off >>= 1) v += __shfl_down(v, off, 64);
  __shared__ float red[4];
  __shared__ int is_last;
  if ((threadIdx.x & 63) == 0) red[threadIdx.x >> 6] = v;
  __syncthreads();
  if (threadIdx.x == 0) {
    const float s = (red[0] + red[1]) + (red[2] + red[3]);
    __hip_atomic_store(&bsum[blockIdx.x], s, __ATOMIC_RELEASE,
                       __HIP_MEMORY_SCOPE_AGENT);
    const unsigned int old = __hip_atomic_fetch_add(
        cnt, 1u, __ATOMIC_ACQ_REL, __HIP_MEMORY_SCOPE_AGENT);
    is_last = (old == RBLOCKS - 1);
  }
  __syncthreads();
  if (is_last) {
    const int t = threadIdx.x;
    float w = 0.0f;
    if (t < RBLOCKS)  // blocks 0..63 are dir0, 64..127 dir1
      w = __hip_atomic_load(&bsum[t], __ATOMIC_ACQUIRE,
                            __HIP_MEMORY_SCOPE_AGENT);
#pragma unroll
    for (int off = 32; off > 0; off >>= 1) w += __shfl_down(w, off, 64);
    if ((t & 63) == 0 && t < RBLOCKS) out[t >> 6] = w * (1.0f / 65536.0f);
  }
}

extern "C" void kernel_launch(void* const* d_in, const int* in_sizes, int n_in,
                              void* d_out, int out_size, void* d_ws, size_t ws_size,
                              hipStream_t stream) {
  const float* pred = (const float*)d_in[0];
  const float* target = (const float*)d_in[1];
  float* out = (float*)d_out;
  float* partial = (float*)d_ws;                              // 4 MiB
  float* bsum = (float*)((char*)d_ws + NSLICE * QT * 4);      // 512 B
  unsigned int* cnt =
      (unsigned int*)((char*)d_ws + NSLICE * QT * 4 + 512);   // 4 B

  chamfer_partial<<<2 * BB * NQC * NSLICE, 256, 0, stream>>>(pred, target,
                                                             partial, cnt);
  chamfer_reduce<<<RBLOCKS, 256, 0, stream>>>((const float4*)partial, bsum,
                                              cnt, out);
}

// Round 8
// 99.949 us; speedup vs baseline: 1.0906x; 1.0906x over previous
//
#include <hip/hip_runtime.h>

#define BB 16
#define NN 4096
#define HQ (BB * NN)        // 65536 queries per direction
#define QT (2 * HQ)         // 131072 total
#define NSLICE 8
#define DBS (NN / NSLICE)   // 512 db points per block
#define WPTS (DBS / 4)      // 128 db points per wave
#define CPTS 8              // points per chunk (s_load_dwordx16 of float2)
#define NITER (WPTS / CPTS) // 16 chunks per wave
#define PQ 16               // queries per lane
#define QW (64 * PQ)        // 1024 queries per block (same set in all 4 waves)
#define NQC (NN / QW)       // 4 query chunks per batch
#define RBLOCKS (QT / 4 / 256)  // 128 reduce blocks

typedef float v16f __attribute__((ext_vector_type(16)));

// Block id bits: slice[0:2], qc[3:4], b[5:8], dir[9]. 1024 blocks.
// Each wave owns a 128-pt quarter of the block's 512-pt db slice, loaded
// 8 points at a time into SGPRs via s_load_dwordx16 (SMEM pipe — zero VALU
// address math, zero LDS in the hot loop). Inner loop is pure v_fma_f32
// (one SGPR operand) + v_min3_f32: per 2 db points per query = 4 fma +
// 1 min3. R3-R6 showed every VGPR-operand formulation pays LDS reads +
// extract movs (or asm spills, R6: WRITE_SIZE 4->20 MB); SGPR operands
// delete all of it. R7 fix: the chunk address is wave-uniform but derived
// from threadIdx (wid), which the compiler treats as divergent — force
// SGPR allocation via readfirstlane on both address halves.
__global__ __launch_bounds__(256, 4) void chamfer_partial(
    const float* __restrict__ pred, const float* __restrict__ target,
    float* __restrict__ partial, unsigned int* __restrict__ cnt) {
  const int bid = blockIdx.x;
  const int slice = bid & (NSLICE - 1);
  const int qc = (bid >> 3) & (NQC - 1);
  const int b = (bid >> 5) & (BB - 1);
  const int dir = bid >> 9;
  const int t = threadIdx.x;
  const int lane = t & 63;
  const int wid = t >> 6;

  if (bid == 0 && t == 0) *cnt = 0;  // arrival counter for reduce (ws poisoned)

  // This lane's 16 queries (same set in all 4 waves; L1/L2-hot, coalesced).
  const float2* __restrict__ qsrc = (const float2*)(dir ? target : pred);
  const int qbase = b * NN + qc * QW + lane;
  float nx[PQ], ny[PQ], acc[PQ];
#pragma unroll
  for (int k = 0; k < PQ; ++k) {
    const float2 Q = qsrc[qbase + k * 64];
    nx[k] = -2.0f * Q.x;
    ny[k] = -2.0f * Q.y;
    acc[k] = 3.4e38f;
  }

  // db = opposite cloud, raw float2, wave-uniform chunk base. Force the
  // byte address into SGPRs (readfirstlane defines it as uniform).
  const float* __restrict__ dsrc = (const float*)(dir ? pred : target);
  const unsigned long long baddr =
      (unsigned long long)(dsrc + 2 * (b * NN + slice * DBS + wid * WPTS));
  const unsigned int blo = __builtin_amdgcn_readfirstlane((unsigned int)baddr);
  const unsigned int bhi =
      __builtin_amdgcn_readfirstlane((unsigned int)(baddr >> 32));
  const unsigned long long ubase = ((unsigned long long)bhi << 32) | blo;

  v16f cur, nxt;
  unsigned long long pcur = ubase;
  // First chunk: blocking load (SMEM latency paid once per wave).
  asm volatile("s_load_dwordx16 %0, %1, 0x0\n\ts_waitcnt lgkmcnt(0)"
               : "=s"(cur)
               : "s"(pcur));
  for (int g = 0; g < NITER; ++g) {
    // Prefetch next chunk (last iter wraps to base: in-bounds, value unused).
    const unsigned long long pnext =
        (g == NITER - 1) ? ubase : (pcur + 8ull * CPTS);
    asm volatile("s_load_dwordx16 %0, %1, 0x0" : "=s"(nxt) : "s"(pnext));

#pragma unroll
    for (int j = 0; j < CPTS; j += 2) {
      const float x0 = cur[2 * j], y0 = cur[2 * j + 1];
      const float x1 = cur[2 * j + 2], y1 = cur[2 * j + 3];
      // |t|^2 once per wave per point.
      const float s0 = __builtin_fmaf(x0, x0, y0 * y0);
      const float s1 = __builtin_fmaf(x1, x1, y1 * y1);
#pragma unroll
      for (int k = 0; k < PQ; ++k) {
        float r0 = __builtin_fmaf(ny[k], y0, s0);   // v_fma(v, s, v)
        r0 = __builtin_fmaf(nx[k], x0, r0);
        float r1 = __builtin_fmaf(ny[k], y1, s1);
        r1 = __builtin_fmaf(nx[k], x1, r1);
        acc[k] = fminf(acc[k], fminf(r0, r1));      // v_min3_f32
      }
    }

    // Drain the prefetch; tying nxt orders any use of it after this wait.
    asm volatile("s_waitcnt lgkmcnt(0)" : "+s"(nxt));
    cur = nxt;
    pcur = pnext;
  }

  // Cross-wave min combine via LDS (16 KB), layout [k][wid][lane]:
  // 64-lane row access = 2 lanes/bank, conflict-free.
  __shared__ float smem[PQ * 4 * 64];
  __syncthreads();
#pragma unroll
  for (int k = 0; k < PQ; ++k) smem[(k * 4 + wid) * 64 + lane] = acc[k];
  __syncthreads();

  // Thread t combines the 4 wave-mins for queries k=wid*4..wid*4+3 and adds
  // q2 = |Q|^2 = 0.25*(nx^2+ny^2).
  const int pbase = slice * QT + dir * HQ + b * NN + qc * QW + lane;
#pragma unroll
  for (int j = 0; j < 4; ++j) {
    const int k = wid * 4 + j;
    const float m = fminf(fminf(smem[(k * 4 + 0) * 64 + lane],
                                smem[(k * 4 + 1) * 64 + lane]),
                          fminf(smem[(k * 4 + 2) * 64 + lane],
                                smem[(k * 4 + 3) * 64 + lane]));
    const float q2 = 0.25f * __builtin_fmaf(nx[k], nx[k], ny[k] * ny[k]);
    partial[pbase + k * 64] = m + q2;
  }
}

// Min over 8 slices (float4-vectorized; values are final d2), block-sum;
// last-arriving block folds the 128 block-sums into the two outputs.
__global__ __launch_bounds__(256) void chamfer_reduce(
    const float4* __restrict__ partial4, float* __restrict__ bsum,
    unsigned int* __restrict__ cnt, float* __restrict__ out) {
  const int i = blockIdx.x * 256 + threadIdx.x;  // 0 .. QT/4, 128 blocks
  float4 m = partial4[i];
#pragma unroll
  for (int s = 1; s < NSLICE; ++s) {
    const float4 w = partial4[s * (QT / 4) + i];
    m.x = fminf(m.x, w.x);
    m.y = fminf(m.y, w.y);
    m.z = fminf(m.z, w.z);
    m.w = fminf(m.w, w.w);
  }
  float v = (m.x + m.y) + (m.z + m.w);

#pragma unroll
  for (int off = 32; off > 0; off >>= 1) v += __shfl_down(v, off, 64);
  __shared__ float red[4];
  __shared__ int is_last;
  if ((threadIdx.x & 63) == 0) red[threadIdx.x >> 6] = v;
  __syncthreads();
  if (threadIdx.x == 0) {
    const float s = (red[0] + red[1]) + (red[2] + red[3]);
    __hip_atomic_store(&bsum[blockIdx.x], s, __ATOMIC_RELEASE,
                       __HIP_MEMORY_SCOPE_AGENT);
    const unsigned int old = __hip_atomic_fetch_add(
        cnt, 1u, __ATOMIC_ACQ_REL, __HIP_MEMORY_SCOPE_AGENT);
    is_last = (old == RBLOCKS - 1);
  }
  __syncthreads();
  if (is_last) {
    const int tt = threadIdx.x;
    float w = 0.0f;
    if (tt < RBLOCKS)  // blocks 0..63 are dir0, 64..127 dir1
      w = __hip_atomic_load(&bsum[tt], __ATOMIC_ACQUIRE,
                            __HIP_MEMORY_SCOPE_AGENT);
#pragma unroll
    for (int off = 32; off > 0; off >>= 1) w += __shfl_down(w, off, 64);
    if ((tt & 63) == 0 && tt < RBLOCKS) out[tt >> 6] = w * (1.0f / 65536.0f);
  }
}

extern "C" void kernel_launch(void* const* d_in, const int* in_sizes, int n_in,
                              void* d_out, int out_size, void* d_ws, size_t ws_size,
                              hipStream_t stream) {
  const float* pred = (const float*)d_in[0];
  const float* target = (const float*)d_in[1];
  float* out = (float*)d_out;
  float* partial = (float*)d_ws;                              // 4 MiB
  float* bsum = (float*)((char*)d_ws + NSLICE * QT * 4);      // 512 B
  unsigned int* cnt =
      (unsigned int*)((char*)d_ws + NSLICE * QT * 4 + 512);   // 4 B

  chamfer_partial<<<2 * BB * NQC * NSLICE, 256, 0, stream>>>(pred, target,
                                                             partial, cnt);
  chamfer_reduce<<<RBLOCKS, 256, 0, stream>>>((const float4*)partial, bsum,
                                              cnt, out);
}